// Round 1
// baseline (178.610 us; speedup 1.0000x reference)
//
#include <hip/hip_runtime.h>
#include <math.h>

// RC thermal model: x' = A x + b0*To(t) + Bq, RK4 with h=30 over T=1e6 steps.
// Closed form per step: x_{t+1} = M x_t + c + al*To[t] + be*To[t+1].
// Parallel affine scan: 16-step chunks (K1) -> hierarchical Hillis-Steele
// scan with precomputed powers M^(16*2^l) (K2a/b/c) -> expansion+write (K3).

#define S_STEPS 999999      // T-1 recurrence steps
#define L0      16          // steps per level-0 chunk
#define C0PAD   65536       // padded chunk count (covers 1,048,576 steps)
#define C0REAL  62500       // ceil(999999/16)
#define BLK1    512         // scan block size
#define NBLK    128         // C0PAD / BLK1
#define NLVL0   9           // log2(BLK1)
#define NLVL1   7           // log2(NBLK)

// ws float offsets
#define OFF_M   0           // 144
#define OFF_C   144         // 12
#define OFF_AL  156         // 12
#define OFF_BE  168         // 12
#define OFF_P   180         // 16*144 = 2304 : P[l] = M^(16*2^l)
#define OFF_TOT 2484        // 128*12
#define OFF_XS  4020        // 128*12
#define OFF_XB  5556        // 65537*12 -> ws end = 792000 floats (~3.2 MB)
#define V0OFF   11213568    // 12,000,000 - 65536*12 : v0 scratch in d_out tail

__device__ inline void mm12(double* C, const double* A_, const double* B_, int t) {
  if (t < 144) {
    int i = t / 12, j = t % 12;
    double s = 0.0;
#pragma unroll
    for (int k = 0; k < 12; ++k) s += A_[i*12+k] * B_[k*12+j];
    C[t] = s;
  }
  __syncthreads();
}

__global__ void setup_kernel(const float* __restrict__ t_eval,
                             const float* __restrict__ x0,
                             const float* __restrict__ A,
                             const float* __restrict__ Bm,
                             const float* __restrict__ loads_raw,
                             const float* __restrict__ areas,
                             float* __restrict__ ws) {
  __shared__ double H[144], H2[144], H3[144], H4[144], Qa[144], Qb[144];
  __shared__ double bq[12], b0[12];
  int t = threadIdx.x;
  double h = (double)t_eval[1] - (double)t_eval[0];
  if (t < 144) H[t] = h * (double)A[t];
  if (t < 12) {
    b0[t] = (double)Bm[t*11];
    double s = 0.0;
    for (int r = 0; r < 10; ++r) {
      double g = 50.0 / (1.0 + exp(-(double)loads_raw[10 + r]));  // gain row
      s += (double)Bm[t*11 + 1 + r] * (g * (double)areas[r]);
    }
    bq[t] = s;
  }
  __syncthreads();
  mm12(H2, H, H, t);     // H^2
  mm12(H3, H2, H, t);    // H^3
  mm12(H4, H2, H2, t);   // H^4
  // forcing vectors (fp64): c=(Nt+Nm+Nn)Bq, al=(Nt+.5Nm)b0, be=(Nn+.5Nm)b0
  if (t < 12) {
    double hb=0,h2b=0,h3b=0,hb0=0,h2b0=0,h3b0=0;
    for (int k = 0; k < 12; ++k) {
      hb  += H[t*12+k]*bq[k];  h2b  += H2[t*12+k]*bq[k];  h3b  += H3[t*12+k]*bq[k];
      hb0 += H[t*12+k]*b0[k];  h2b0 += H2[t*12+k]*b0[k];  h3b0 += H3[t*12+k]*b0[k];
    }
    double h6 = h / 6.0;
    ws[OFF_C  + t] = (float)(h6*(6.0*bq[t] + 3.0*hb + h2b + 0.25*h3b));
    ws[OFF_AL + t] = (float)(h6*(3.0*b0[t] + 2.0*hb0 + 0.75*h2b0 + 0.25*h3b0));
    ws[OFF_BE + t] = (float)(h6*(3.0*b0[t] + hb0 + 0.25*h2b0));
  }
  if (t < 144) {
    int i = t/12, j = t%12;
    double m = (i==j ? 1.0 : 0.0) + H[t] + 0.5*H2[t] + H3[t]/6.0 + H4[t]/24.0;
    Qa[t] = m;
    ws[OFF_M + t] = (float)m;
  }
  __syncthreads();
  // repeated squaring: after iter sq, src = M^(2^(sq+1)); need 2^4..2^19
  double* src = Qa; double* dst = Qb;
  for (int sq = 0; sq < 19; ++sq) {
    mm12(dst, src, src, t);
    double* tmp = src; src = dst; dst = tmp;
    if (sq >= 3 && t < 144) ws[OFF_P + (sq-3)*144 + t] = (float)src[t];
    __syncthreads();
  }
}

__global__ void __launch_bounds__(256) chunk_fold(
    const float* __restrict__ ws, const float* __restrict__ To,
    const float* __restrict__ x0, float* __restrict__ v0) {
  int g = blockIdx.x * 256 + threadIdx.x;   // 0..65535
  float Mv[144];
#pragma unroll
  for (int i = 0; i < 36; ++i) {
    float4 q = reinterpret_cast<const float4*>(ws + OFF_M)[i];
    Mv[4*i+0]=q.x; Mv[4*i+1]=q.y; Mv[4*i+2]=q.z; Mv[4*i+3]=q.w;
  }
  float cv[12], al[12], be[12];
#pragma unroll
  for (int i = 0; i < 12; ++i) { cv[i]=ws[OFF_C+i]; al[i]=ws[OFF_AL+i]; be[i]=ws[OFF_BE+i]; }
  float x[12];
#pragma unroll
  for (int i = 0; i < 12; ++i) x[i] = 0.f;
  if (g == 0) {
#pragma unroll
    for (int i = 0; i < 12; ++i) x[i] = x0[i];   // fold x0 into chunk 0
  }
  int base = g * L0;
#pragma unroll
  for (int s = 0; s < L0; ++s) {
    int tt = base + s;
    bool real = (tt < S_STEPS);
    float tot = 0.f, ton = 0.f;
    if (real) { tot = To[tt]; ton = To[tt+1]; }
    float xn[12];
#pragma unroll
    for (int i = 0; i < 12; ++i) {
      float acc = real ? (cv[i] + al[i]*tot + be[i]*ton) : 0.f;
#pragma unroll
      for (int k = 0; k < 12; ++k) acc = fmaf(Mv[i*12+k], x[k], acc);
      xn[i] = acc;
    }
#pragma unroll
    for (int i = 0; i < 12; ++i) x[i] = xn[i];
  }
  float4* vp = reinterpret_cast<float4*>(v0 + (size_t)g*12);
  vp[0] = make_float4(x[0],x[1],x[2],x[3]);
  vp[1] = make_float4(x[4],x[5],x[6],x[7]);
  vp[2] = make_float4(x[8],x[9],x[10],x[11]);
}

// Hillis-Steele affine scan over BLK1 elements; combine uses value-only
// matvec with the known power P[l] = M^(16*2^l). FINAL=false: write block
// totals. FINAL=true: inject block start state into element 0, write all
// chunk-boundary states Xb[g+1].
template <bool FINAL>
__global__ void __launch_bounds__(512) scan_k(
    float* __restrict__ ws, const float* __restrict__ v0,
    const float* __restrict__ x0) {
  __shared__ float lw[BLK1][13];        // +1 pad: conflict-free stride
  __shared__ float Pc[NLVL0][144];
  int k = threadIdx.x, b = blockIdx.x;
  for (int idx = k; idx < NLVL0*144; idx += BLK1)
    Pc[idx/144][idx % 144] = ws[OFF_P + idx];
  int g = b * BLK1 + k;
  float w[12];
#pragma unroll
  for (int i = 0; i < 12; ++i) w[i] = v0[(size_t)g*12 + i];
  if (FINAL && k == 0) {
    // w = M^16 * Xstart[b] + w
    float wn[12];
#pragma unroll
    for (int i = 0; i < 12; ++i) {
      float acc = w[i];
      for (int j = 0; j < 12; ++j)
        acc = fmaf(ws[OFF_P + i*12 + j], ws[OFF_XS + b*12 + j], acc);
      wn[i] = acc;
    }
#pragma unroll
    for (int i = 0; i < 12; ++i) w[i] = wn[i];
  }
#pragma unroll
  for (int i = 0; i < 12; ++i) lw[k][i] = w[i];
  __syncthreads();
  for (int l = 0; l < NLVL0; ++l) {
    int off = 1 << l;
    float nb[12];
    if (k >= off) {
#pragma unroll
      for (int i = 0; i < 12; ++i) nb[i] = lw[k-off][i];
    }
    __syncthreads();
    if (k >= off) {
#pragma unroll
      for (int i = 0; i < 12; ++i) {
        float acc = w[i];
#pragma unroll
        for (int j = 0; j < 12; ++j) acc = fmaf(Pc[l][i*12+j], nb[j], acc);
        w[i] = acc;
      }
#pragma unroll
      for (int i = 0; i < 12; ++i) lw[k][i] = w[i];
    }
    __syncthreads();
  }
  if (!FINAL) {
    if (k == BLK1-1) {
#pragma unroll
      for (int i = 0; i < 12; ++i) ws[OFF_TOT + b*12 + i] = w[i];
    }
  } else {
#pragma unroll
    for (int i = 0; i < 12; ++i) ws[OFF_XB + ((size_t)g+1)*12 + i] = w[i];
    if (g == 0) {
#pragma unroll
      for (int i = 0; i < 12; ++i) ws[OFF_XB + i] = x0[i];
    }
  }
}

__global__ void __launch_bounds__(128) scan_totals(float* __restrict__ ws) {
  __shared__ float lw[NBLK][13];
  int k = threadIdx.x;
  float w[12];
#pragma unroll
  for (int i = 0; i < 12; ++i) w[i] = ws[OFF_TOT + k*12 + i];
#pragma unroll
  for (int i = 0; i < 12; ++i) lw[k][i] = w[i];
  __syncthreads();
  for (int l = 0; l < NLVL1; ++l) {
    int off = 1 << l;
    float nb[12];
    if (k >= off) {
#pragma unroll
      for (int i = 0; i < 12; ++i) nb[i] = lw[k-off][i];
    }
    __syncthreads();
    if (k >= off) {
      const float* P = ws + OFF_P + (NLVL0 + l)*144;   // M^(8192*2^l)
#pragma unroll
      for (int i = 0; i < 12; ++i) {
        float acc = w[i];
#pragma unroll
        for (int j = 0; j < 12; ++j) acc = fmaf(P[i*12+j], nb[j], acc);
        w[i] = acc;
      }
#pragma unroll
      for (int i = 0; i < 12; ++i) lw[k][i] = w[i];
    }
    __syncthreads();
  }
  if (k == 0) {
#pragma unroll
    for (int i = 0; i < 12; ++i) ws[OFF_XS + i] = 0.f;   // x0 already in v0[0]
  }
  if (k < NBLK-1) {
#pragma unroll
    for (int i = 0; i < 12; ++i) ws[OFF_XS + (k+1)*12 + i] = w[i];
  }
}

__global__ void __launch_bounds__(256) expand_write(
    const float* __restrict__ ws, const float* __restrict__ To,
    const float* __restrict__ x0, float* __restrict__ out) {
  int g = blockIdx.x * 256 + threadIdx.x;
  if (g == 0) {
#pragma unroll
    for (int i = 0; i < 12; ++i) out[i] = x0[i];   // row 0
  }
  if (g >= C0REAL) return;
  float Mv[144];
#pragma unroll
  for (int i = 0; i < 36; ++i) {
    float4 q = reinterpret_cast<const float4*>(ws + OFF_M)[i];
    Mv[4*i+0]=q.x; Mv[4*i+1]=q.y; Mv[4*i+2]=q.z; Mv[4*i+3]=q.w;
  }
  float cv[12], al[12], be[12];
#pragma unroll
  for (int i = 0; i < 12; ++i) { cv[i]=ws[OFF_C+i]; al[i]=ws[OFF_AL+i]; be[i]=ws[OFF_BE+i]; }
  float x[12];
#pragma unroll
  for (int i = 0; i < 12; ++i) x[i] = ws[OFF_XB + (size_t)g*12 + i];
  int base = g * L0;
#pragma unroll
  for (int s = 0; s < L0; ++s) {
    int tt = base + s;
    if (tt >= S_STEPS) break;
    float tot = To[tt], ton = To[tt+1];
    float xn[12];
#pragma unroll
    for (int i = 0; i < 12; ++i) {
      float acc = cv[i] + al[i]*tot + be[i]*ton;
#pragma unroll
      for (int kk = 0; kk < 12; ++kk) acc = fmaf(Mv[i*12+kk], x[kk], acc);
      xn[i] = acc;
    }
    float4* op = reinterpret_cast<float4*>(out + (size_t)(tt+1)*12);
    op[0] = make_float4(xn[0],xn[1],xn[2],xn[3]);
    op[1] = make_float4(xn[4],xn[5],xn[6],xn[7]);
    op[2] = make_float4(xn[8],xn[9],xn[10],xn[11]);
#pragma unroll
    for (int i = 0; i < 12; ++i) x[i] = xn[i];
  }
}

extern "C" void kernel_launch(void* const* d_in, const int* in_sizes, int n_in,
                              void* d_out, int out_size, void* d_ws, size_t ws_size,
                              hipStream_t stream) {
  const float* t_eval    = (const float*)d_in[0];
  const float* x0        = (const float*)d_in[1];
  const float* A         = (const float*)d_in[2];
  const float* B         = (const float*)d_in[3];
  const float* To        = (const float*)d_in[4];
  const float* loads_raw = (const float*)d_in[5];
  const float* areas     = (const float*)d_in[6];
  float* out = (float*)d_out;
  float* ws  = (float*)d_ws;
  float* v0  = out + V0OFF;   // scratch in d_out tail, overwritten by K3

  setup_kernel<<<1, 256, 0, stream>>>(t_eval, x0, A, B, loads_raw, areas, ws);
  chunk_fold<<<C0PAD/256, 256, 0, stream>>>(ws, To, x0, v0);
  scan_k<false><<<NBLK, BLK1, 0, stream>>>(ws, v0, x0);
  scan_totals<<<1, NBLK, 0, stream>>>(ws);
  scan_k<true><<<NBLK, BLK1, 0, stream>>>(ws, v0, x0);
  expand_write<<<(C0REAL + 255)/256, 256, 0, stream>>>(ws, To, x0, out);
}